// Round 1
// baseline (419.743 us; speedup 1.0000x reference)
//
#include <hip/hip_runtime.h>
#include <math.h>

// Problem shape (fixed by reference setup_inputs):
//   B=32, H=64, W=64, C=256, NHWC layout (C contiguous).
//   Outputs: x (B,H,W,C) fp32 then gate (B,1,1,C) fp32, concatenated flat.
#define B_ 32
#define HW_ 4096          // 64*64
#define C_ 256
#define C4_ 64            // C/4
#define NCHUNK 32         // spatial chunks per batch in pass 1
#define CHUNK 128         // HW_/NCHUNK positions per chunk

// Native vector type — required for __builtin_nontemporal_store (HIP's
// float4 is a class and is rejected by the builtin).
typedef float vfloat4 __attribute__((ext_vector_type(4)));

// ---------------- Kernel 1: partial reduction + fused per-batch gate ----------------
// Grid: B*NCHUNK blocks, 256 threads. Thread layout: t = pg*64 + c4,
// pg in [0,4) position-group, c4 in [0,64) float4 channel group.
// Each thread strides positions by 4, float4 over channels (16B/lane).
//
// Gate fusion: after writing its partials, each block device-fences and bumps
// counters[b]; the LAST block of batch b (threadfence-reduction pattern)
// finishes the reduction and computes the gate for that batch. This removes
// the serial 32-block gate_kernel (which idled ~220 CUs on the critical path
// between the two BW-bound passes) and overlaps gate math with other
// batches' pool work. Cross-XCD visibility: release = __threadfence() before
// the atomic bump, acquire = __threadfence() after observing the last count.
__global__ __launch_bounds__(256) void pool_gate_kernel(
    const float* __restrict__ in, float* __restrict__ ws_sum,
    float* __restrict__ ws_max, unsigned int* __restrict__ counters,
    const float* __restrict__ factor, const float* __restrict__ W1,
    const float* __restrict__ b1, const float* __restrict__ gamma,
    const float* __restrict__ beta, const float* __restrict__ bn_mean,
    const float* __restrict__ bn_var, const float* __restrict__ Wg,
    const float* __restrict__ bg, const float* __restrict__ gumbel,
    float* __restrict__ ws_gate, float* __restrict__ out_gate) {
  const int b = blockIdx.x >> 5;   // / NCHUNK
  const int k = blockIdx.x & 31;   // % NCHUNK
  const int t = threadIdx.x;
  const int c4 = t & 63;
  const int pg = t >> 6;           // 0..3

  const float4* in4 = (const float4*)in;
  // float4 index of (b, pos = k*CHUNK + pg, channel-group c4)
  long base = (long)b * (HW_ * C4_) + (long)(k * CHUNK + pg) * C4_ + c4;

  float4 s = make_float4(0.f, 0.f, 0.f, 0.f);
  float4 m = make_float4(-INFINITY, -INFINITY, -INFINITY, -INFINITY);
#pragma unroll 8
  for (int p = 0; p < CHUNK; p += 4) {
    float4 v = in4[base + (long)p * C4_];
    s.x += v.x; s.y += v.y; s.z += v.z; s.w += v.w;
    m.x = fmaxf(m.x, v.x); m.y = fmaxf(m.y, v.y);
    m.z = fmaxf(m.z, v.z); m.w = fmaxf(m.w, v.w);
  }

  __shared__ float4 ssum[256];
  __shared__ float4 smax[256];
  __shared__ int winner_s;
  ssum[t] = s;
  smax[t] = m;
  __syncthreads();

  if (pg == 0) {
#pragma unroll
    for (int q = 1; q < 4; ++q) {
      float4 s2 = ssum[q * 64 + c4];
      float4 m2 = smax[q * 64 + c4];
      s.x += s2.x; s.y += s2.y; s.z += s2.z; s.w += s2.w;
      m.x = fmaxf(m.x, m2.x); m.y = fmaxf(m.y, m2.y);
      m.z = fmaxf(m.z, m2.z); m.w = fmaxf(m.w, m2.w);
    }
    float4* wsum4 = (float4*)ws_sum;
    float4* wmax4 = (float4*)ws_max;
    wsum4[(b * NCHUNK + k) * C4_ + c4] = s;
    wmax4[(b * NCHUNK + k) * C4_ + c4] = m;
  }

  // --- last-block-per-batch election (CUB threadfence-reduction pattern) ---
  __threadfence();           // release: partial stores visible device-wide
  __syncthreads();           // all storers have fenced before the bump
  if (t == 0) {
    unsigned prev = atomicAdd(&counters[b], 1u);
    winner_s = (prev == NCHUNK - 1) ? 1 : 0;
  }
  __syncthreads();
  if (!winner_s) return;
  __threadfence();           // acquire: see all 32 blocks' partials

  // ---------------- fused gate computation (one block per batch) ----------------
  const int j = t;  // channel

  float sj = 0.f;
  float mj = -INFINITY;
#pragma unroll 8
  for (int kk = 0; kk < NCHUNK; ++kk) {
    sj += ws_sum[(b * NCHUNK + kk) * C_ + j];
    mj = fmaxf(mj, ws_max[(b * NCHUNK + kk) * C_ + j]);
  }

  // softmax over the 2 blend factors
  float a0 = factor[0], a1 = factor[1];
  float mx = fmaxf(a0, a1);
  float e0 = expf(a0 - mx), e1 = expf(a1 - mx);
  float inv = 1.f / (e0 + e1);
  float f0 = e0 * inv, f1 = e1 * inv;

  __shared__ float pool[C_];
  pool[j] = (sj * (1.0f / (float)HW_)) * f0 + mj * f1;
  __syncthreads();

  // h[j] = sum_c pool[c] * W1[c,j] + b1[j]; 4 independent FMA chains for ILP
  float h0 = 0.f, h1 = 0.f, h2 = 0.f, h3 = 0.f;
#pragma unroll 8
  for (int c = 0; c < C_; c += 4) {
    h0 = fmaf(pool[c + 0], W1[(c + 0) * C_ + j], h0);
    h1 = fmaf(pool[c + 1], W1[(c + 1) * C_ + j], h1);
    h2 = fmaf(pool[c + 2], W1[(c + 2) * C_ + j], h2);
    h3 = fmaf(pool[c + 3], W1[(c + 3) * C_ + j], h3);
  }
  float h = ((h0 + h1) + (h2 + h3)) + b1[j];
  // BatchNorm (inference) + ReLU
  h = gamma[j] * (h - bn_mean[j]) * rsqrtf(bn_var[j] + 1e-3f) + beta[j];
  h = fmaxf(h, 0.f);

  // grouped 1x1 conv -> 2 logits, + gumbel; hard sample = argmax
  float z0 = fmaf(h, Wg[j * 2 + 0], bg[j * 2 + 0]) + gumbel[(b * C_ + j) * 2 + 0];
  float z1 = fmaf(h, Wg[j * 2 + 1], bg[j * 2 + 1]) + gumbel[(b * C_ + j) * 2 + 1];
  // argmax picks index 0 on ties -> gate = 1 iff z1 > z0 strictly
  float g = (z1 > z0) ? 1.0f : 0.0f;

  ws_gate[b * C_ + j] = g;
  out_gate[b * C_ + j] = g;
}

// ---------------- Kernel 2: x = inputs * gate[b,c] ----------------
// 8192 blocks x 256 threads; each thread handles 4 float4s at the same
// channel-group (one gate load reused 4x), 4 independent load->mul->store
// chains for memory-level parallelism. Nontemporal stores keep the
// L3-resident input from being evicted by the output stream.
__global__ __launch_bounds__(256) void apply_gate_kernel(
    const float* __restrict__ in, const float* __restrict__ ws_gate,
    float* __restrict__ out) {
  const vfloat4* in4 = (const vfloat4*)in;
  const vfloat4* g4 = (const vfloat4*)ws_gate;
  vfloat4* out4 = (vfloat4*)out;

  const int t = threadIdx.x;
  const int lane = t & 63;   // channel-group c4
  const int grp = t >> 6;    // 0..3

  // Block covers 1024 consecutive float4s = 16 positions x 64 channel-groups.
  long base = (long)blockIdx.x * 1024;
  long i0 = base + (long)grp * 256 + lane;  // then +64, +128, +192

  int b = (int)(base >> 18);  // 2^18 float4s per batch; constant per block
  vfloat4 g = g4[b * C4_ + lane];

  vfloat4 v0 = in4[i0];
  vfloat4 v1 = in4[i0 + 64];
  vfloat4 v2 = in4[i0 + 128];
  vfloat4 v3 = in4[i0 + 192];

  v0 *= g;
  v1 *= g;
  v2 *= g;
  v3 *= g;

  __builtin_nontemporal_store(v0, &out4[i0]);
  __builtin_nontemporal_store(v1, &out4[i0 + 64]);
  __builtin_nontemporal_store(v2, &out4[i0 + 128]);
  __builtin_nontemporal_store(v3, &out4[i0 + 192]);
}

extern "C" void kernel_launch(void* const* d_in, const int* in_sizes, int n_in,
                              void* d_out, int out_size, void* d_ws, size_t ws_size,
                              hipStream_t stream) {
  const float* inputs  = (const float*)d_in[0];
  const float* factor  = (const float*)d_in[1];
  const float* W1      = (const float*)d_in[2];
  const float* b1      = (const float*)d_in[3];
  const float* gamma   = (const float*)d_in[4];
  const float* beta    = (const float*)d_in[5];
  const float* bn_mean = (const float*)d_in[6];
  const float* bn_var  = (const float*)d_in[7];
  const float* Wg      = (const float*)d_in[8];
  const float* bg      = (const float*)d_in[9];
  const float* gumbel  = (const float*)d_in[10];

  float* out_x = (float*)d_out;                          // B*H*W*C floats
  float* out_gate = (float*)d_out + (long)B_ * HW_ * C_; // B*C floats

  // Workspace layout (floats):
  float* ws_sum  = (float*)d_ws;                   // B*NCHUNK*C = 262144
  float* ws_max  = ws_sum + B_ * NCHUNK * C_;      // 262144
  float* ws_gate = ws_max + B_ * NCHUNK * C_;      // B*C = 8192
  unsigned int* counters = (unsigned int*)(ws_gate + B_ * C_);  // B uints

  // Workspace is poisoned between iterations -> counters must be zeroed.
  // 128-byte async memset is graph-capturable (stream memset node).
  hipMemsetAsync(counters, 0, B_ * sizeof(unsigned int), stream);

  pool_gate_kernel<<<B_ * NCHUNK, 256, 0, stream>>>(
      inputs, ws_sum, ws_max, counters, factor, W1, b1, gamma, beta, bn_mean,
      bn_var, Wg, bg, gumbel, ws_gate, out_gate);

  const long n4 = (long)B_ * HW_ * C4_;  // 2^23 float4s
  apply_gate_kernel<<<(int)(n4 / 1024), 256, 0, stream>>>(inputs, ws_gate, out_x);
}

// Round 2
// 282.902 us; speedup vs baseline: 1.4837x; 1.4837x over previous
//
#include <hip/hip_runtime.h>
#include <math.h>

// Problem shape (fixed by reference setup_inputs):
//   B=32, H=64, W=64, C=256, NHWC layout (C contiguous).
//   Outputs: x (B,H,W,C) fp32 then gate (B,1,1,C) fp32, concatenated flat.
#define B_ 32
#define HW_ 4096          // 64*64
#define C_ 256
#define C4_ 64            // C/4
#define NCHUNK 32         // spatial chunks per batch in pass 1
#define CHUNK 128         // HW_/NCHUNK positions per chunk

// Native vector type — required for __builtin_nontemporal_store (HIP's
// float4 is a class and is rejected by the builtin).
typedef float vfloat4 __attribute__((ext_vector_type(4)));

// ---------------- Kernel 1: partial reduction + fused per-batch gate ----------------
// Grid: B*NCHUNK blocks, 256 threads. Thread layout: t = pg*64 + c4,
// pg in [0,4) position-group, c4 in [0,64) float4 channel group.
//
// Gate fusion, attempt 2. Round-1 post-mortem: __threadfence() on gfx950
// compiles to buffer_wbl2/buffer_inv L2 cache maintenance (per-XCD L2s are
// non-coherent); 1024 blocks each flushing L2 serialized for ~190 us
// (VALUBusy 0.7%, HBM 4%). This version uses NO fences: the 2 KB/block of
// partials are written with agent-scope relaxed atomic stores (compiler
// emits the sc0/sc1 bits -> coherent at the L3 point, no L2 flush), then
// wave 0 drains its own stores with s_waitcnt vmcnt(0) and bumps the
// per-batch counter with a relaxed agent-scope atomicAdd. The last arriver
// reads all partials back with agent-scope loads (bypassing its possibly
// stale local L2) and computes the gate for that batch. Happens-before:
// each block's stores complete at the coherence point before its counter
// bump completes there; winner observing count==32 therefore observes all
// partials.
__global__ __launch_bounds__(256) void pool_gate_kernel(
    const float* __restrict__ in, float* __restrict__ ws_sum,
    float* __restrict__ ws_max, unsigned int* __restrict__ counters,
    const float* __restrict__ factor, const float* __restrict__ W1,
    const float* __restrict__ b1, const float* __restrict__ gamma,
    const float* __restrict__ beta, const float* __restrict__ bn_mean,
    const float* __restrict__ bn_var, const float* __restrict__ Wg,
    const float* __restrict__ bg, const float* __restrict__ gumbel,
    float* __restrict__ ws_gate, float* __restrict__ out_gate) {
  const int b = blockIdx.x >> 5;   // / NCHUNK
  const int k = blockIdx.x & 31;   // % NCHUNK
  const int t = threadIdx.x;
  const int c4 = t & 63;
  const int pg = t >> 6;           // 0..3 == wave id

  const float4* in4 = (const float4*)in;
  // float4 index of (b, pos = k*CHUNK + pg, channel-group c4)
  long base = (long)b * (HW_ * C4_) + (long)(k * CHUNK + pg) * C4_ + c4;

  float4 s = make_float4(0.f, 0.f, 0.f, 0.f);
  float4 m = make_float4(-INFINITY, -INFINITY, -INFINITY, -INFINITY);
#pragma unroll 8
  for (int p = 0; p < CHUNK; p += 4) {
    float4 v = in4[base + (long)p * C4_];
    s.x += v.x; s.y += v.y; s.z += v.z; s.w += v.w;
    m.x = fmaxf(m.x, v.x); m.y = fmaxf(m.y, v.y);
    m.z = fmaxf(m.z, v.z); m.w = fmaxf(m.w, v.w);
  }

  __shared__ float4 ssum[256];
  __shared__ float4 smax[256];
  __shared__ int winner_s;
  ssum[t] = s;
  smax[t] = m;
  __syncthreads();

  if (pg == 0) {  // wave 0 only (t == lane, 0..63)
#pragma unroll
    for (int q = 1; q < 4; ++q) {
      float4 s2 = ssum[q * 64 + c4];
      float4 m2 = smax[q * 64 + c4];
      s.x += s2.x; s.y += s2.y; s.z += s2.z; s.w += s2.w;
      m.x = fmaxf(m.x, m2.x); m.y = fmaxf(m.y, m2.y);
      m.z = fmaxf(m.z, m2.z); m.w = fmaxf(m.w, m2.w);
    }
    // Agent-scope (device-coherent) stores of this chunk's partials: visible
    // at the coherence point once vmcnt retires — no cache flush needed.
    const int o = ((b * NCHUNK + k) * C4_ + c4) * 4;
    __hip_atomic_store(&ws_sum[o + 0], s.x, __ATOMIC_RELAXED, __HIP_MEMORY_SCOPE_AGENT);
    __hip_atomic_store(&ws_sum[o + 1], s.y, __ATOMIC_RELAXED, __HIP_MEMORY_SCOPE_AGENT);
    __hip_atomic_store(&ws_sum[o + 2], s.z, __ATOMIC_RELAXED, __HIP_MEMORY_SCOPE_AGENT);
    __hip_atomic_store(&ws_sum[o + 3], s.w, __ATOMIC_RELAXED, __HIP_MEMORY_SCOPE_AGENT);
    __hip_atomic_store(&ws_max[o + 0], m.x, __ATOMIC_RELAXED, __HIP_MEMORY_SCOPE_AGENT);
    __hip_atomic_store(&ws_max[o + 1], m.y, __ATOMIC_RELAXED, __HIP_MEMORY_SCOPE_AGENT);
    __hip_atomic_store(&ws_max[o + 2], m.z, __ATOMIC_RELAXED, __HIP_MEMORY_SCOPE_AGENT);
    __hip_atomic_store(&ws_max[o + 3], m.w, __ATOMIC_RELAXED, __HIP_MEMORY_SCOPE_AGENT);
    // Drain wave 0's stores to the coherence point, THEN bump the counter.
    // asm memory clobber stops the compiler reordering the atomic above it.
    asm volatile("s_waitcnt vmcnt(0)" ::: "memory");
    if (t == 0) {
      unsigned prev = __hip_atomic_fetch_add(&counters[b], 1u,
                                             __ATOMIC_RELAXED,
                                             __HIP_MEMORY_SCOPE_AGENT);
      winner_s = (prev == NCHUNK - 1) ? 1 : 0;
    }
  }
  __syncthreads();
  if (!winner_s) return;

  // ---------------- fused gate computation (last block of batch b) ----------------
  const int j = t;  // channel

  float sj = 0.f;
  float mj = -INFINITY;
#pragma unroll 8
  for (int kk = 0; kk < NCHUNK; ++kk) {
    // Agent-scope loads: bypass this XCD's (possibly stale) L2.
    float ps = __hip_atomic_load(&ws_sum[(b * NCHUNK + kk) * C_ + j],
                                 __ATOMIC_RELAXED, __HIP_MEMORY_SCOPE_AGENT);
    float pm = __hip_atomic_load(&ws_max[(b * NCHUNK + kk) * C_ + j],
                                 __ATOMIC_RELAXED, __HIP_MEMORY_SCOPE_AGENT);
    sj += ps;
    mj = fmaxf(mj, pm);
  }

  // softmax over the 2 blend factors
  float a0 = factor[0], a1 = factor[1];
  float mx = fmaxf(a0, a1);
  float e0 = expf(a0 - mx), e1 = expf(a1 - mx);
  float inv = 1.f / (e0 + e1);
  float f0 = e0 * inv, f1 = e1 * inv;

  __shared__ float pool[C_];
  pool[j] = (sj * (1.0f / (float)HW_)) * f0 + mj * f1;
  __syncthreads();

  // h[j] = sum_c pool[c] * W1[c,j] + b1[j]; 4 independent FMA chains for ILP
  float h0 = 0.f, h1 = 0.f, h2 = 0.f, h3 = 0.f;
#pragma unroll 8
  for (int c = 0; c < C_; c += 4) {
    h0 = fmaf(pool[c + 0], W1[(c + 0) * C_ + j], h0);
    h1 = fmaf(pool[c + 1], W1[(c + 1) * C_ + j], h1);
    h2 = fmaf(pool[c + 2], W1[(c + 2) * C_ + j], h2);
    h3 = fmaf(pool[c + 3], W1[(c + 3) * C_ + j], h3);
  }
  float h = ((h0 + h1) + (h2 + h3)) + b1[j];
  // BatchNorm (inference) + ReLU
  h = gamma[j] * (h - bn_mean[j]) * rsqrtf(bn_var[j] + 1e-3f) + beta[j];
  h = fmaxf(h, 0.f);

  // grouped 1x1 conv -> 2 logits, + gumbel; hard sample = argmax
  float z0 = fmaf(h, Wg[j * 2 + 0], bg[j * 2 + 0]) + gumbel[(b * C_ + j) * 2 + 0];
  float z1 = fmaf(h, Wg[j * 2 + 1], bg[j * 2 + 1]) + gumbel[(b * C_ + j) * 2 + 1];
  // argmax picks index 0 on ties -> gate = 1 iff z1 > z0 strictly
  float g = (z1 > z0) ? 1.0f : 0.0f;

  ws_gate[b * C_ + j] = g;
  out_gate[b * C_ + j] = g;
}

// ---------------- Kernel 2: x = inputs * gate[b,c] ----------------
// 8192 blocks x 256 threads; each thread handles 4 float4s at the same
// channel-group (one gate load reused 4x), 4 independent load->mul->store
// chains for memory-level parallelism. Nontemporal stores keep the
// L3-resident input from being evicted by the output stream.
__global__ __launch_bounds__(256) void apply_gate_kernel(
    const float* __restrict__ in, const float* __restrict__ ws_gate,
    float* __restrict__ out) {
  const vfloat4* in4 = (const vfloat4*)in;
  const vfloat4* g4 = (const vfloat4*)ws_gate;
  vfloat4* out4 = (vfloat4*)out;

  const int t = threadIdx.x;
  const int lane = t & 63;   // channel-group c4
  const int grp = t >> 6;    // 0..3

  // Block covers 1024 consecutive float4s = 16 positions x 64 channel-groups.
  long base = (long)blockIdx.x * 1024;
  long i0 = base + (long)grp * 256 + lane;  // then +64, +128, +192

  int b = (int)(base >> 18);  // 2^18 float4s per batch; constant per block
  vfloat4 g = g4[b * C4_ + lane];

  vfloat4 v0 = in4[i0];
  vfloat4 v1 = in4[i0 + 64];
  vfloat4 v2 = in4[i0 + 128];
  vfloat4 v3 = in4[i0 + 192];

  v0 *= g;
  v1 *= g;
  v2 *= g;
  v3 *= g;

  __builtin_nontemporal_store(v0, &out4[i0]);
  __builtin_nontemporal_store(v1, &out4[i0 + 64]);
  __builtin_nontemporal_store(v2, &out4[i0 + 128]);
  __builtin_nontemporal_store(v3, &out4[i0 + 192]);
}

extern "C" void kernel_launch(void* const* d_in, const int* in_sizes, int n_in,
                              void* d_out, int out_size, void* d_ws, size_t ws_size,
                              hipStream_t stream) {
  const float* inputs  = (const float*)d_in[0];
  const float* factor  = (const float*)d_in[1];
  const float* W1      = (const float*)d_in[2];
  const float* b1      = (const float*)d_in[3];
  const float* gamma   = (const float*)d_in[4];
  const float* beta    = (const float*)d_in[5];
  const float* bn_mean = (const float*)d_in[6];
  const float* bn_var  = (const float*)d_in[7];
  const float* Wg      = (const float*)d_in[8];
  const float* bg      = (const float*)d_in[9];
  const float* gumbel  = (const float*)d_in[10];

  float* out_x = (float*)d_out;                          // B*H*W*C floats
  float* out_gate = (float*)d_out + (long)B_ * HW_ * C_; // B*C floats

  // Workspace layout (floats):
  float* ws_sum  = (float*)d_ws;                   // B*NCHUNK*C = 262144
  float* ws_max  = ws_sum + B_ * NCHUNK * C_;      // 262144
  float* ws_gate = ws_max + B_ * NCHUNK * C_;      // B*C = 8192
  unsigned int* counters = (unsigned int*)(ws_gate + B_ * C_);  // B uints

  // Workspace is poisoned between iterations -> counters must be zeroed.
  // 128-byte async memset is graph-capturable (stream memset node).
  hipMemsetAsync(counters, 0, B_ * sizeof(unsigned int), stream);

  pool_gate_kernel<<<B_ * NCHUNK, 256, 0, stream>>>(
      inputs, ws_sum, ws_max, counters, factor, W1, b1, gamma, beta, bn_mean,
      bn_var, Wg, bg, gumbel, ws_gate, out_gate);

  const long n4 = (long)B_ * HW_ * C4_;  // 2^23 float4s
  apply_gate_kernel<<<(int)(n4 / 1024), 256, 0, stream>>>(inputs, ws_gate, out_x);
}